// Round 7
// baseline (248.299 us; speedup 1.0000x reference)
//
#include <hip/hip_runtime.h>
#include <hip/hip_bf16.h>
#include <stdint.h>

typedef unsigned short u16;
typedef __bf16 bf16x8 __attribute__((ext_vector_type(8)));
typedef float  f32x4  __attribute__((ext_vector_type(4)));
typedef u16    u16x8  __attribute__((ext_vector_type(8)));
typedef u16    u16x4  __attribute__((ext_vector_type(4)));

// float -> bf16 RNE
__device__ __forceinline__ u16 f2bf(float f) {
  union { float f; unsigned u; } v; v.f = f;
  unsigned u = v.u;
  unsigned r = u + 0x7FFFu + ((u >> 16) & 1u);
  return (u16)(r >> 16);
}

__device__ __forceinline__ void gld_lds16(const void* g, void* l) {
  __builtin_amdgcn_global_load_lds(
      (const __attribute__((address_space(1))) void*)g,
      (__attribute__((address_space(3))) void*)l, 16, 0, 0);
}

// ---- detect int32 vs int64 index storage ----------------------------------
__global__ void detect_idx_width(const unsigned* __restrict__ w, int* __restrict__ flag) {
  unsigned v = w[threadIdx.x * 2 + 1];
  unsigned long long any = __ballot(v != 0u);
  if (threadIdx.x == 0) *flag = (any != 0ull) ? 1 : 0;  // 1 = int32, 0 = int64
}

// ---- x: f32 -> bf16 --------------------------------------------------------
__global__ __launch_bounds__(256) void cvt_x_kernel(const float4* __restrict__ x,
                                                    u16* __restrict__ xb, long n8) {
  long i = (long)blockIdx.x * blockDim.x + threadIdx.x;
  long stride = (long)gridDim.x * blockDim.x;
  for (; i < n8; i += stride) {
    float4 a = x[2 * i];
    float4 b = x[2 * i + 1];
    u16x8 r;
    r[0] = f2bf(a.x); r[1] = f2bf(a.y); r[2] = f2bf(a.z); r[3] = f2bf(a.w);
    r[4] = f2bf(b.x); r[5] = f2bf(b.y); r[6] = f2bf(b.z); r[7] = f2bf(b.w);
    *(u16x8*)(xb + 8 * i) = r;
  }
}

// ---- W: values[w_idx] -> bf16 ---------------------------------------------
__global__ __launch_bounds__(256) void dequant_w_kernel(const int4* __restrict__ widx,
                                                        const float* __restrict__ values,
                                                        u16* __restrict__ wb,
                                                        const int* __restrict__ flag, long n4) {
  const bool is32 = (*flag != 0);
  long i = (long)blockIdx.x * blockDim.x + threadIdx.x;
  long stride = (long)gridDim.x * blockDim.x;
  for (; i < n4; i += stride) {
    int i0, i1, i2, i3;
    if (is32) {
      int4 v = widx[i];
      i0 = v.x; i1 = v.y; i2 = v.z; i3 = v.w;
    } else {
      int4 a = widx[2 * i];
      int4 b = widx[2 * i + 1];
      i0 = a.x; i1 = a.z; i2 = b.x; i3 = b.z;
    }
    u16x4 r;
    r[0] = f2bf(values[i0]); r[1] = f2bf(values[i1]);
    r[2] = f2bf(values[i2]); r[3] = f2bf(values[i3]);
    *(u16x4*)(wb + 4 * i) = r;
  }
}

// ===========================================================================
// 256x256 8-phase bf16 GEMM — R7: R5's phase-pipelined afr reads (consume one
// phase after issue) + __launch_bounds__(512, 1). LDS (160 KiB) already
// limits to 1 block/CU, so the previous ",2" only capped VGPRs at 128 and
// forced the afr double-buffer to spill (R5's 232 MB WRITE_SIZE). With 256
// VGPR/wave (2 waves/SIMD x 256 = full register file) the read-ahead fits.
// A: 2 x 32KB LDS bufs; B: 3 x 32KB (depth-3 staging).
// ===========================================================================
#define VMW(n) asm volatile("s_waitcnt vmcnt(" #n ")" ::: "memory")
#define SB0    __builtin_amdgcn_sched_barrier(0)
#define PH_BAR __builtin_amdgcn_s_barrier()

__global__ __launch_bounds__(512, 1) void gemm256_kernel(
    const u16* __restrict__ Xb, const u16* __restrict__ Wb,
    const float* __restrict__ bias, float* __restrict__ C,
    int Nout, int Kin) {
  __shared__ __align__(16) char lds[163840];  // A:[0,64K) 2 bufs; B:[64K,160K) 3 bufs

  const int tid  = threadIdx.x;
  const int lane = tid & 63;
  const int wave = tid >> 6;
  const int wr = wave >> 2;   // 0..1  (M half)
  const int wc = wave & 3;    // 0..3  (N quarter)

  // bijective XCD swizzle (m204)
  const int nwg = gridDim.x;
  const int bid = blockIdx.x;
  const int q8 = nwg >> 3, r8 = nwg & 7;
  const int xcd = bid & 7;
  const int wg = (xcd < r8 ? xcd * (q8 + 1) : r8 * (q8 + 1) + (xcd - r8) * q8) + (bid >> 3);

  const int tiles_n = Nout / 256;
  const long brow = (long)(wg / tiles_n) * 256;
  const long bcol = (long)(wg % tiles_n) * 256;

  const size_t rowbytes = (size_t)Kin * 2;

  // staging: inverse-swizzled global source + linear LDS dest (rule #21)
  const int f0  = tid * 16;
  const int f1  = f0 + 8192;
  const int rS0 = f0 >> 7;        // 0..63
  const int rS1 = rS0 + 64;       // 64..127 (same (rS&7) -> same cS)
  const int cS  = (f0 & 127) ^ ((rS0 & 7) << 4);

  const char* gA00 = (const char*)Xb + (size_t)(brow +       rS0) * rowbytes + cS;
  const char* gA01 = (const char*)Xb + (size_t)(brow +       rS1) * rowbytes + cS;
  const char* gA10 = (const char*)Xb + (size_t)(brow + 128 + rS0) * rowbytes + cS;
  const char* gA11 = (const char*)Xb + (size_t)(brow + 128 + rS1) * rowbytes + cS;
  const char* gB00 = (const char*)Wb + (size_t)(bcol +       rS0) * rowbytes + cS;
  const char* gB01 = (const char*)Wb + (size_t)(bcol +       rS1) * rowbytes + cS;
  const char* gB10 = (const char*)Wb + (size_t)(bcol + 128 + rS0) * rowbytes + cS;
  const char* gB11 = (const char*)Wb + (size_t)(bcol + 128 + rS1) * rowbytes + cS;

#define STAGE_AH(base_, h, t) { \
  gld_lds16(gA##h##0 + (size_t)(t) * 128, lds + (base_) + (h) * 16384 + f0); \
  gld_lds16(gA##h##1 + (size_t)(t) * 128, lds + (base_) + (h) * 16384 + f1); }
#define STAGE_BH(base_, h, t) { \
  gld_lds16(gB##h##0 + (size_t)(t) * 128, lds + (base_) + (h) * 16384 + f0); \
  gld_lds16(gB##h##1 + (size_t)(t) * 128, lds + (base_) + (h) * 16384 + f1); }

  // fragment read addressing (swizzled)
  const int fr   = lane & 15;
  const int kb   = (lane >> 4) * 16;
  const int xsw  = (fr & 7) << 4;
  const int colx0 = kb ^ xsw;          // ks = 0
  const int colx1 = (64 + kb) ^ xsw;   // ks = 1
  const int aOff = wr * 16384 + fr * 128;
  const int bOff = (wc >> 1) * 16384 + ((wc & 1) * 64 + fr) * 128;

  bf16x8 afr0[2][2];   // afr parity buffers: MFMA(q) consumes afr(q&1)
  bf16x8 afr1[2][2];
  bf16x8 bfrE[4][2];   // B-frags, even tiles
  bf16x8 bfrO[4][2];   // B-frags, odd tiles
  f32x4  acc[8][4] = {};

// read A-slice q of tile in abase_ into DST (4 ds_read_b128)
#define READ_AQ(abase_, q, DST) { \
  const char* ab = lds + (abase_) + aOff + (q) * 4096; \
  DST[0][0] = *(const bf16x8*)(ab + colx0); \
  DST[0][1] = *(const bf16x8*)(ab + colx1); \
  DST[1][0] = *(const bf16x8*)(ab + 2048 + colx0); \
  DST[1][1] = *(const bf16x8*)(ab + 2048 + colx1); }

// prefetch 2 of 4 B column-tiles (ni = lo, lo+1) into dst regs
#define READ_BPF(bbase_, dst, lo) { \
  const char* bb = lds + (bbase_) + bOff; \
  dst[(lo)][0]     = *(const bf16x8*)(bb + (lo) * 2048 + colx0); \
  dst[(lo)][1]     = *(const bf16x8*)(bb + (lo) * 2048 + colx1); \
  dst[(lo) + 1][0] = *(const bf16x8*)(bb + ((lo) + 1) * 2048 + colx0); \
  dst[(lo) + 1][1] = *(const bf16x8*)(bb + ((lo) + 1) * 2048 + colx1); }

#define MFMA_Q(q, AF, BF) { \
  __builtin_amdgcn_s_setprio(1); \
  _Pragma("unroll") for (int m2 = 0; m2 < 2; ++m2) \
  _Pragma("unroll") for (int ni = 0; ni < 4; ++ni) { \
    acc[(q)*2+m2][ni] = __builtin_amdgcn_mfma_f32_16x16x32_bf16(AF[m2][0], BF[ni][0], acc[(q)*2+m2][ni], 0, 0, 0); \
    acc[(q)*2+m2][ni] = __builtin_amdgcn_mfma_f32_16x16x32_bf16(AF[m2][1], BF[ni][1], acc[(q)*2+m2][ni], 0, 0, 0); } \
  __builtin_amdgcn_s_setprio(0); }

// phase: {reads, stage} pinned before barrier#1; MFMA between barriers
// consumes ONLY reads issued in earlier phases (drained under the previous
// phase's MFMA window); WT (vmcnt) after MFMA.
#define PHASE(RDS, STG, MF, WT) { \
  RDS; STG; SB0; PH_BAR; SB0; MF; SB0; WT; PH_BAR; }

  const int aB0 = 0, aB1 = 32768;
  int bR0 = 65536, bR1 = 98304, bR2 = 131072;  // B(t), B(t+1), B(t+2)
  const int NT = Kin >> 6;

  // prologue: A(0)->aB0, B(0..2); drain; preload bfrE=B(0), afr0=A(0,q0)
  STAGE_AH(aB0, 0, 0); STAGE_AH(aB0, 1, 0);
  STAGE_BH(bR0, 0, 0); STAGE_BH(bR0, 1, 0);
  if (NT > 1) { STAGE_BH(bR1, 0, 1); STAGE_BH(bR1, 1, 1); }
  if (NT > 2) { STAGE_BH(bR2, 0, 2); STAGE_BH(bR2, 1, 2); }
  VMW(0);
  PH_BAR;
  READ_BPF(bR0, bfrE, 0); READ_BPF(bR0, bfrE, 2);
  READ_AQ(aB0, 0, afr0);

  const int NITER = NT >> 1;
  // Group g ledger (4 phases): stages ph0:A0(g+1) ph1:A1(g+1) ph2:B0(g+3)
  // ph3:B1(g+3). VMW(2)@ph2-end: outstanding 10 -> completes B(g+2)+A(g+1),
  // leaves B0(g+3). ph3 reads afr(g+1,q0) AFTER that {VMW, barrier} (safe).
  // afr: MFMA(q) consumes parity q&1, phase q reads afr(q+1) into parity
  // (q&1)^1. Tail (g+3>=NT): VMW(0) at ph2 (counted wait would leave
  // A1(g+1) in flight).
  for (int i = 0; i < NITER; ++i) {
    const int t0 = i * 2;
    const bool a1 = (t0 + 1 < NT);   // always true in-loop
    const bool a2 = (t0 + 2 < NT);
    const bool b3 = (t0 + 3 < NT);
    const bool b4 = (t0 + 4 < NT);

    // ---- even group g = t0: A in aB0, bfr cur = bfrE, next = bfrO (bR1)
    PHASE(READ_AQ(aB0, 1, afr1),
          { if (a1) STAGE_AH(aB1, 0, t0 + 1); },
          MFMA_Q(0, afr0, bfrE), (void)0);
    PHASE({ READ_AQ(aB0, 2, afr0); READ_BPF(bR1, bfrO, 0); },
          { if (a1) STAGE_AH(aB1, 1, t0 + 1); },
          MFMA_Q(1, afr1, bfrE), (void)0);
    PHASE({ READ_AQ(aB0, 3, afr1); READ_BPF(bR1, bfrO, 2); },
          { if (b3) STAGE_BH(bR0, 0, t0 + 3); },
          MFMA_Q(2, afr0, bfrE),
          { if (b3) { VMW(2); } else { VMW(0); } });
    PHASE({ if (a1) READ_AQ(aB1, 0, afr0); },
          { if (b3) STAGE_BH(bR0, 1, t0 + 3); },
          MFMA_Q(3, afr1, bfrE), (void)0);

    // ---- odd group g = t0+1: A in aB1, bfr cur = bfrO, next = bfrE (bR2)
    PHASE(READ_AQ(aB1, 1, afr1),
          { if (a2) STAGE_AH(aB0, 0, t0 + 2); },
          MFMA_Q(0, afr0, bfrO), (void)0);
    PHASE({ READ_AQ(aB1, 2, afr0); if (a2) READ_BPF(bR2, bfrE, 0); },
          { if (a2) STAGE_AH(aB0, 1, t0 + 2); },
          MFMA_Q(1, afr1, bfrO), (void)0);
    PHASE({ READ_AQ(aB1, 3, afr1); if (a2) READ_BPF(bR2, bfrE, 2); },
          { if (b4) STAGE_BH(bR1, 0, t0 + 4); },
          MFMA_Q(2, afr0, bfrO),
          { if (b4) { VMW(2); } else { VMW(0); } });
    PHASE({ if (a2) READ_AQ(aB0, 0, afr0); },
          { if (b4) STAGE_BH(bR1, 1, t0 + 4); },
          MFMA_Q(3, afr1, bfrO), (void)0);

    // rotate B bufs: (bR0,bR1,bR2) <- (bR2,bR0,bR1)
    int tmp = bR0; bR0 = bR2; bR2 = bR1; bR1 = tmp;
  }

  // epilogue: C/D layout col = lane&15, row = (lane>>4)*4 + j
  const int cm = (lane >> 4) * 4;
  const int cn = lane & 15;
  float bv[4];
#pragma unroll
  for (int ni = 0; ni < 4; ++ni) bv[ni] = bias[bcol + wc * 64 + ni * 16 + cn];

#pragma unroll
  for (int mi = 0; mi < 8; ++mi) {
    const long row0 = brow + wr * 128 + mi * 16 + cm;
#pragma unroll
    for (int ni = 0; ni < 4; ++ni) {
      const long col = bcol + wc * 64 + ni * 16 + cn;
#pragma unroll
      for (int j = 0; j < 4; ++j)
        C[(row0 + j) * (long)Nout + col] = acc[mi][ni][j] + bv[ni];
    }
  }
#undef STAGE_AH
#undef STAGE_BH
#undef READ_AQ
#undef READ_BPF
#undef MFMA_Q
#undef PHASE
}

// ---- 128x128 m97-structure fallback (verified in R1) -----------------------
__global__ __launch_bounds__(256, 2) void gemm128_kernel(
    const u16* __restrict__ Xb, const u16* __restrict__ Wb,
    const float* __restrict__ bias, float* __restrict__ C,
    int Nout, int Kin) {
  __shared__ __align__(16) u16 As[128 * 32];
  __shared__ __align__(16) u16 Bs[128 * 32];
  const int tid  = threadIdx.x;
  const int lane = tid & 63;
  const int wave = tid >> 6;
  const int wr = wave >> 1, wc = wave & 1;
  const int nwg = gridDim.x, bid = blockIdx.x;
  const int q = nwg >> 3, r8 = nwg & 7;
  const int xcd = bid & 7;
  const int wg = (xcd < r8 ? xcd * (q + 1) : r8 * (q + 1) + (xcd - r8) * q) + (bid >> 3);
  const int tiles_n = Nout / 128;
  const long brow = (long)(wg / tiles_n) * 128;
  const long bcol = (long)(wg % tiles_n) * 128;
  const int f0 = tid * 16, f1 = f0 + 4096;
  const size_t rowbytes = (size_t)Kin * 2;
  const char* gA0 = (const char*)Xb + (size_t)(brow + (f0 >> 6)) * rowbytes + (f0 & 63);
  const char* gA1 = (const char*)Xb + (size_t)(brow + (f1 >> 6)) * rowbytes + (f1 & 63);
  const char* gB0 = (const char*)Wb + (size_t)(bcol + (f0 >> 6)) * rowbytes + (f0 & 63);
  const char* gB1 = (const char*)Wb + (size_t)(bcol + (f1 >> 6)) * rowbytes + (f1 & 63);
  char* lA0 = (char*)As + f0; char* lA1 = (char*)As + f1;
  char* lB0 = (char*)Bs + f0; char* lB1 = (char*)Bs + f1;
  const int fr = lane & 15, kb = (lane >> 4) * 16;
  const char* aptr[4]; const char* bptr[4];
#pragma unroll
  for (int i = 0; i < 4; ++i) {
    aptr[i] = (const char*)As + (wr * 64 + i * 16 + fr) * 64 + kb;
    bptr[i] = (const char*)Bs + (wc * 64 + i * 16 + fr) * 64 + kb;
  }
  f32x4 acc[4][4] = {};
  for (int kk = 0; kk < Kin; kk += 32) {
    const size_t ko = (size_t)kk * 2;
    gld_lds16(gA0 + ko, lA0); gld_lds16(gA1 + ko, lA1);
    gld_lds16(gB0 + ko, lB0); gld_lds16(gB1 + ko, lB1);
    __syncthreads();
    bf16x8 a[4], b[4];
#pragma unroll
    for (int i = 0; i < 4; ++i) a[i] = *(const bf16x8*)aptr[i];
#pragma unroll
    for (int i = 0; i < 4; ++i) b[i] = *(const bf16x8*)bptr[i];
#pragma unroll
    for (int mi = 0; mi < 4; ++mi)
#pragma unroll
      for (int ni = 0; ni < 4; ++ni)
        acc[mi][ni] = __builtin_amdgcn_mfma_f32_16x16x32_bf16(a[mi], b[ni], acc[mi][ni], 0, 0, 0);
    __syncthreads();
  }
  const int cm = (lane >> 4) * 4, cn = lane & 15;
  float bv[4];
#pragma unroll
  for (int ni = 0; ni < 4; ++ni) bv[ni] = bias[bcol + wc * 64 + ni * 16 + cn];
#pragma unroll
  for (int mi = 0; mi < 4; ++mi) {
    const long row0 = brow + wr * 64 + mi * 16 + cm;
#pragma unroll
    for (int ni = 0; ni < 4; ++ni) {
      const long col = bcol + wc * 64 + ni * 16 + cn;
#pragma unroll
      for (int j = 0; j < 4; ++j)
        C[(row0 + j) * (long)Nout + col] = acc[mi][ni][j] + bv[ni];
    }
  }
}

// ---- naive fallback --------------------------------------------------------
__global__ void fallback_kernel(const float* __restrict__ x, const float* __restrict__ values,
                                const int* __restrict__ widx, const float* __restrict__ bias,
                                float* __restrict__ out, const int* __restrict__ flag,
                                int NT, int IF, int OF) {
  const int o = blockIdx.x * blockDim.x + threadIdx.x;
  const int t = blockIdx.y;
  if (o >= OF || t >= NT) return;
  const bool is32 = (*flag != 0);
  const float* xr = x + (size_t)t * IF;
  float sum = 0.f;
  if (is32) {
    const int* w = widx + (size_t)o * IF;
    for (int k = 0; k < IF; ++k) sum += xr[k] * values[w[k]];
  } else {
    const long long* w = (const long long*)widx + (size_t)o * IF;
    for (int k = 0; k < IF; ++k) sum += xr[k] * values[(int)w[k]];
  }
  out[(size_t)t * OF + o] = sum + bias[o];
}

extern "C" void kernel_launch(void* const* d_in, const int* in_sizes, int n_in,
                              void* d_out, int out_size, void* d_ws, size_t ws_size,
                              hipStream_t stream) {
  const float* x      = (const float*)d_in[0];
  const float* values = (const float*)d_in[1];
  const int*   widx   = (const int*)d_in[2];
  const float* bias   = (const float*)d_in[3];
  float* out = (float*)d_out;

  const long xsz = in_sizes[0];
  const int  OF  = in_sizes[3];
  const long wsz = in_sizes[2];
  const int  IF  = (int)(wsz / OF);
  const int  NTOK = (int)(xsz / IF);

  u16* xb = (u16*)d_ws;
  u16* wb = xb + (size_t)NTOK * IF;
  int* flag = (int*)(wb + (size_t)OF * IF);
  const size_t need = ((size_t)NTOK * IF + (size_t)OF * IF) * sizeof(u16) + 64;

  const bool pre_ok = (ws_size >= need) && ((xsz % 8) == 0) && ((wsz % 4) == 0);
  const bool f256 = pre_ok && (IF % 128 == 0) && (IF >= 256) &&
                    (NTOK % 256 == 0) && (OF % 256 == 0);
  const bool f128 = pre_ok && (IF % 32 == 0) && (NTOK % 128 == 0) && (OF % 128 == 0);

  if (f256 || f128) {
    hipLaunchKernelGGL(detect_idx_width, dim3(1), dim3(64), 0, stream,
                       (const unsigned*)widx, flag);
    hipLaunchKernelGGL(cvt_x_kernel, dim3(2048), dim3(256), 0, stream,
                       (const float4*)x, xb, xsz / 8);
    hipLaunchKernelGGL(dequant_w_kernel, dim3(2048), dim3(256), 0, stream,
                       (const int4*)widx, values, wb, (const int*)flag, wsz / 4);
    if (f256) {
      const int grid = (NTOK / 256) * (OF / 256);
      hipLaunchKernelGGL(gemm256_kernel, dim3(grid), dim3(512), 0, stream,
                         xb, wb, bias, out, OF, IF);
    } else {
      const int grid = (NTOK / 128) * (OF / 128);
      hipLaunchKernelGGL(gemm128_kernel, dim3(grid), dim3(256), 0, stream,
                         xb, wb, bias, out, OF, IF);
    }
  } else {
    int* flag2 = (int*)d_ws;
    hipLaunchKernelGGL(detect_idx_width, dim3(1), dim3(64), 0, stream,
                       (const unsigned*)widx, flag2);
    hipLaunchKernelGGL(fallback_kernel, dim3((OF + 255) / 256, NTOK), dim3(256), 0, stream,
                       x, values, widx, bias, out, (const int*)flag2, NTOK, IF, OF);
  }
}

// Round 8
// 170.219 us; speedup vs baseline: 1.4587x; 1.4587x over previous
//
#include <hip/hip_runtime.h>
#include <hip/hip_bf16.h>
#include <stdint.h>

typedef unsigned short u16;
typedef __bf16 bf16x8 __attribute__((ext_vector_type(8)));
typedef float  f32x4  __attribute__((ext_vector_type(4)));
typedef u16    u16x8  __attribute__((ext_vector_type(8)));
typedef u16    u16x4  __attribute__((ext_vector_type(4)));

// float -> bf16 RNE
__device__ __forceinline__ u16 f2bf(float f) {
  union { float f; unsigned u; } v; v.f = f;
  unsigned u = v.u;
  unsigned r = u + 0x7FFFu + ((u >> 16) & 1u);
  return (u16)(r >> 16);
}

__device__ __forceinline__ void gld_lds16(const void* g, void* l) {
  __builtin_amdgcn_global_load_lds(
      (const __attribute__((address_space(1))) void*)g,
      (__attribute__((address_space(3))) void*)l, 16, 0, 0);
}

// ---- detect int32 vs int64 index storage ----------------------------------
__global__ void detect_idx_width(const unsigned* __restrict__ w, int* __restrict__ flag) {
  unsigned v = w[threadIdx.x * 2 + 1];
  unsigned long long any = __ballot(v != 0u);
  if (threadIdx.x == 0) *flag = (any != 0ull) ? 1 : 0;  // 1 = int32, 0 = int64
}

// ---- x: f32 -> bf16 --------------------------------------------------------
__global__ __launch_bounds__(256) void cvt_x_kernel(const float4* __restrict__ x,
                                                    u16* __restrict__ xb, long n8) {
  long i = (long)blockIdx.x * blockDim.x + threadIdx.x;
  long stride = (long)gridDim.x * blockDim.x;
  for (; i < n8; i += stride) {
    float4 a = x[2 * i];
    float4 b = x[2 * i + 1];
    u16x8 r;
    r[0] = f2bf(a.x); r[1] = f2bf(a.y); r[2] = f2bf(a.z); r[3] = f2bf(a.w);
    r[4] = f2bf(b.x); r[5] = f2bf(b.y); r[6] = f2bf(b.z); r[7] = f2bf(b.w);
    *(u16x8*)(xb + 8 * i) = r;
  }
}

// ---- W: values[w_idx] -> bf16 ---------------------------------------------
__global__ __launch_bounds__(256) void dequant_w_kernel(const int4* __restrict__ widx,
                                                        const float* __restrict__ values,
                                                        u16* __restrict__ wb,
                                                        const int* __restrict__ flag, long n4) {
  const bool is32 = (*flag != 0);
  long i = (long)blockIdx.x * blockDim.x + threadIdx.x;
  long stride = (long)gridDim.x * blockDim.x;
  for (; i < n4; i += stride) {
    int i0, i1, i2, i3;
    if (is32) {
      int4 v = widx[i];
      i0 = v.x; i1 = v.y; i2 = v.z; i3 = v.w;
    } else {
      int4 a = widx[2 * i];
      int4 b = widx[2 * i + 1];
      i0 = a.x; i1 = a.z; i2 = b.x; i3 = b.z;
    }
    u16x4 r;
    r[0] = f2bf(values[i0]); r[1] = f2bf(values[i1]);
    r[2] = f2bf(values[i2]); r[3] = f2bf(values[i3]);
    *(u16x4*)(wb + 4 * i) = r;
  }
}

// ===========================================================================
// 256x256 8-phase bf16 GEMM — R8: phase-pipelined afr reads (R5/R7 ledger,
// correctness-proven) + staging addresses refactored to UNIFORM scalar bases
// + one 32-bit per-thread voffset per matrix. This frees the 8 persistent
// 64-bit pointers (~16 arch VGPRs) to fund the afr double-buffer within the
// hard 128-arch-VGPR budget (256 unified - 128 AGPR acc @ 2 waves/SIMD).
// A: 2 x 32KB LDS bufs; B: 3 x 32KB (depth-3 staging).
// ===========================================================================
#define VMW(n) asm volatile("s_waitcnt vmcnt(" #n ")" ::: "memory")
#define SB0    __builtin_amdgcn_sched_barrier(0)
#define PH_BAR __builtin_amdgcn_s_barrier()

__global__ __launch_bounds__(512, 1) void gemm256_kernel(
    const u16* __restrict__ Xb, const u16* __restrict__ Wb,
    const float* __restrict__ bias, float* __restrict__ C,
    int Nout, int Kin) {
  __shared__ __align__(16) char lds[163840];  // A:[0,64K) 2 bufs; B:[64K,160K) 3 bufs

  const int tid  = threadIdx.x;
  const int lane = tid & 63;
  const int wave = tid >> 6;
  const int wr = wave >> 2;   // 0..1  (M half)
  const int wc = wave & 3;    // 0..3  (N quarter)

  // bijective XCD swizzle (m204)
  const int nwg = gridDim.x;
  const int bid = blockIdx.x;
  const int q8 = nwg >> 3, r8 = nwg & 7;
  const int xcd = bid & 7;
  const int wg = (xcd < r8 ? xcd * (q8 + 1) : r8 * (q8 + 1) + (xcd - r8) * q8) + (bid >> 3);

  const int tiles_n = Nout / 256;
  const long brow = (long)(wg / tiles_n) * 256;
  const long bcol = (long)(wg % tiles_n) * 256;

  const long rowb = (long)Kin * 2;      // row bytes
  const long rstep = 64 * rowb;         // +64 rows (uniform)
  const long hstep = 128 * rowb;        // +128 rows (uniform)

  // staging: inverse-swizzled global source + linear LDS dest (rule #21).
  // Address = uniform_base (SGPR, folded SALU) + 32-bit per-thread voff.
  const int f0  = tid * 16;
  const int f1  = f0 + 8192;
  const int rS0 = f0 >> 7;        // 0..63
  const int cS  = (f0 & 127) ^ ((rS0 & 7) << 4);
  const int voff = (int)(rS0 * rowb) + cS;   // per-thread, 32-bit

  const char* uA = (const char*)Xb + (size_t)brow * rowb;   // uniform
  const char* uB = (const char*)Wb + (size_t)bcol * rowb;   // uniform

#define STAGE_AH(base_, h, t) { \
  gld_lds16(uA + (size_t)(h) * hstep + (size_t)(t) * 128 + voff,         lds + (base_) + (h) * 16384 + f0); \
  gld_lds16(uA + (size_t)(h) * hstep + (size_t)(t) * 128 + rstep + voff, lds + (base_) + (h) * 16384 + f1); }
#define STAGE_BH(base_, h, t) { \
  gld_lds16(uB + (size_t)(h) * hstep + (size_t)(t) * 128 + voff,         lds + (base_) + (h) * 16384 + f0); \
  gld_lds16(uB + (size_t)(h) * hstep + (size_t)(t) * 128 + rstep + voff, lds + (base_) + (h) * 16384 + f1); }

  // fragment read addressing (swizzled)
  const int fr   = lane & 15;
  const int kb   = (lane >> 4) * 16;
  const int xsw  = (fr & 7) << 4;
  const int colx0 = kb ^ xsw;          // ks = 0
  const int colx1 = (64 + kb) ^ xsw;   // ks = 1
  const int aOff = wr * 16384 + fr * 128;
  const int bOff = (wc >> 1) * 16384 + ((wc & 1) * 64 + fr) * 128;

  bf16x8 afr0[2][2];   // afr parity buffers: MFMA(q) consumes afr(q&1)
  bf16x8 afr1[2][2];
  bf16x8 bfrE[4][2];   // B-frags, even tiles
  bf16x8 bfrO[4][2];   // B-frags, odd tiles
  f32x4  acc[8][4] = {};

// read A-slice q of tile in abase_ into DST (4 ds_read_b128)
#define READ_AQ(abase_, q, DST) { \
  const char* ab = lds + (abase_) + aOff + (q) * 4096; \
  DST[0][0] = *(const bf16x8*)(ab + colx0); \
  DST[0][1] = *(const bf16x8*)(ab + colx1); \
  DST[1][0] = *(const bf16x8*)(ab + 2048 + colx0); \
  DST[1][1] = *(const bf16x8*)(ab + 2048 + colx1); }

// prefetch 2 of 4 B column-tiles (ni = lo, lo+1) into dst regs
#define READ_BPF(bbase_, dst, lo) { \
  const char* bb = lds + (bbase_) + bOff; \
  dst[(lo)][0]     = *(const bf16x8*)(bb + (lo) * 2048 + colx0); \
  dst[(lo)][1]     = *(const bf16x8*)(bb + (lo) * 2048 + colx1); \
  dst[(lo) + 1][0] = *(const bf16x8*)(bb + ((lo) + 1) * 2048 + colx0); \
  dst[(lo) + 1][1] = *(const bf16x8*)(bb + ((lo) + 1) * 2048 + colx1); }

#define MFMA_Q(q, AF, BF) { \
  __builtin_amdgcn_s_setprio(1); \
  _Pragma("unroll") for (int m2 = 0; m2 < 2; ++m2) \
  _Pragma("unroll") for (int ni = 0; ni < 4; ++ni) { \
    acc[(q)*2+m2][ni] = __builtin_amdgcn_mfma_f32_16x16x32_bf16(AF[m2][0], BF[ni][0], acc[(q)*2+m2][ni], 0, 0, 0); \
    acc[(q)*2+m2][ni] = __builtin_amdgcn_mfma_f32_16x16x32_bf16(AF[m2][1], BF[ni][1], acc[(q)*2+m2][ni], 0, 0, 0); } \
  __builtin_amdgcn_s_setprio(0); }

// phase: {reads, stage} pinned before barrier#1; MFMA between barriers
// consumes ONLY reads issued in earlier phases (drained under the previous
// phase's MFMA window); WT (vmcnt) after MFMA.
#define PHASE(RDS, STG, MF, WT) { \
  RDS; STG; SB0; PH_BAR; SB0; MF; SB0; WT; PH_BAR; }

  const int aB0 = 0, aB1 = 32768;
  int bR0 = 65536, bR1 = 98304, bR2 = 131072;  // B(t), B(t+1), B(t+2)
  const int NT = Kin >> 6;

  // prologue: A(0)->aB0, B(0..2); drain; preload bfrE=B(0), afr0=A(0,q0)
  STAGE_AH(aB0, 0, 0); STAGE_AH(aB0, 1, 0);
  STAGE_BH(bR0, 0, 0); STAGE_BH(bR0, 1, 0);
  if (NT > 1) { STAGE_BH(bR1, 0, 1); STAGE_BH(bR1, 1, 1); }
  if (NT > 2) { STAGE_BH(bR2, 0, 2); STAGE_BH(bR2, 1, 2); }
  VMW(0);
  PH_BAR;
  READ_BPF(bR0, bfrE, 0); READ_BPF(bR0, bfrE, 2);
  READ_AQ(aB0, 0, afr0);

  const int NITER = NT >> 1;
  // Group g ledger (4 phases): stages ph0:A0(g+1) ph1:A1(g+1) ph2:B0(g+3)
  // ph3:B1(g+3). VMW(2)@ph2-end: outstanding 10 -> completes B(g+2)+A(g+1),
  // leaves B0(g+3). ph3 reads afr(g+1,q0) AFTER that {VMW, barrier} (safe).
  // afr: MFMA(q) consumes parity q&1, phase q reads afr(q+1) into parity
  // (q&1)^1. Tail (g+3>=NT): VMW(0) at ph2 (counted wait would leave
  // A1(g+1) in flight).
  for (int i = 0; i < NITER; ++i) {
    const int t0 = i * 2;
    const bool a1 = (t0 + 1 < NT);   // always true in-loop
    const bool a2 = (t0 + 2 < NT);
    const bool b3 = (t0 + 3 < NT);
    const bool b4 = (t0 + 4 < NT);

    // ---- even group g = t0: A in aB0, bfr cur = bfrE, next = bfrO (bR1)
    PHASE(READ_AQ(aB0, 1, afr1),
          { if (a1) STAGE_AH(aB1, 0, t0 + 1); },
          MFMA_Q(0, afr0, bfrE), (void)0);
    PHASE({ READ_AQ(aB0, 2, afr0); READ_BPF(bR1, bfrO, 0); },
          { if (a1) STAGE_AH(aB1, 1, t0 + 1); },
          MFMA_Q(1, afr1, bfrE), (void)0);
    PHASE({ READ_AQ(aB0, 3, afr1); READ_BPF(bR1, bfrO, 2); },
          { if (b3) STAGE_BH(bR0, 0, t0 + 3); },
          MFMA_Q(2, afr0, bfrE),
          { if (b3) { VMW(2); } else { VMW(0); } });
    PHASE({ if (a1) READ_AQ(aB1, 0, afr0); },
          { if (b3) STAGE_BH(bR0, 1, t0 + 3); },
          MFMA_Q(3, afr1, bfrE), (void)0);

    // ---- odd group g = t0+1: A in aB1, bfr cur = bfrO, next = bfrE (bR2)
    PHASE(READ_AQ(aB1, 1, afr1),
          { if (a2) STAGE_AH(aB0, 0, t0 + 2); },
          MFMA_Q(0, afr0, bfrO), (void)0);
    PHASE({ READ_AQ(aB1, 2, afr0); if (a2) READ_BPF(bR2, bfrE, 0); },
          { if (a2) STAGE_AH(aB0, 1, t0 + 2); },
          MFMA_Q(1, afr1, bfrO), (void)0);
    PHASE({ READ_AQ(aB1, 3, afr1); if (a2) READ_BPF(bR2, bfrE, 2); },
          { if (b4) STAGE_BH(bR1, 0, t0 + 4); },
          MFMA_Q(2, afr0, bfrO),
          { if (b4) { VMW(2); } else { VMW(0); } });
    PHASE({ if (a2) READ_AQ(aB0, 0, afr0); },
          { if (b4) STAGE_BH(bR1, 1, t0 + 4); },
          MFMA_Q(3, afr1, bfrO), (void)0);

    // rotate B bufs: (bR0,bR1,bR2) <- (bR2,bR0,bR1)
    int tmp = bR0; bR0 = bR2; bR2 = bR1; bR1 = tmp;
  }

  // epilogue: C/D layout col = lane&15, row = (lane>>4)*4 + j
  const int cm = (lane >> 4) * 4;
  const int cn = lane & 15;
  float bv[4];
#pragma unroll
  for (int ni = 0; ni < 4; ++ni) bv[ni] = bias[bcol + wc * 64 + ni * 16 + cn];

#pragma unroll
  for (int mi = 0; mi < 8; ++mi) {
    const long row0 = brow + wr * 128 + mi * 16 + cm;
#pragma unroll
    for (int ni = 0; ni < 4; ++ni) {
      const long col = bcol + wc * 64 + ni * 16 + cn;
#pragma unroll
      for (int j = 0; j < 4; ++j)
        C[(row0 + j) * (long)Nout + col] = acc[mi][ni][j] + bv[ni];
    }
  }
#undef STAGE_AH
#undef STAGE_BH
#undef READ_AQ
#undef READ_BPF
#undef MFMA_Q
#undef PHASE
}

// ---- 128x128 m97-structure fallback (verified in R1) -----------------------
__global__ __launch_bounds__(256, 2) void gemm128_kernel(
    const u16* __restrict__ Xb, const u16* __restrict__ Wb,
    const float* __restrict__ bias, float* __restrict__ C,
    int Nout, int Kin) {
  __shared__ __align__(16) u16 As[128 * 32];
  __shared__ __align__(16) u16 Bs[128 * 32];
  const int tid  = threadIdx.x;
  const int lane = tid & 63;
  const int wave = tid >> 6;
  const int wr = wave >> 1, wc = wave & 1;
  const int nwg = gridDim.x, bid = blockIdx.x;
  const int q = nwg >> 3, r8 = nwg & 7;
  const int xcd = bid & 7;
  const int wg = (xcd < r8 ? xcd * (q + 1) : r8 * (q + 1) + (xcd - r8) * q) + (bid >> 3);
  const int tiles_n = Nout / 128;
  const long brow = (long)(wg / tiles_n) * 128;
  const long bcol = (long)(wg % tiles_n) * 128;
  const int f0 = tid * 16, f1 = f0 + 4096;
  const size_t rowbytes = (size_t)Kin * 2;
  const char* gA0 = (const char*)Xb + (size_t)(brow + (f0 >> 6)) * rowbytes + (f0 & 63);
  const char* gA1 = (const char*)Xb + (size_t)(brow + (f1 >> 6)) * rowbytes + (f1 & 63);
  const char* gB0 = (const char*)Wb + (size_t)(bcol + (f0 >> 6)) * rowbytes + (f0 & 63);
  const char* gB1 = (const char*)Wb + (size_t)(bcol + (f1 >> 6)) * rowbytes + (f1 & 63);
  char* lA0 = (char*)As + f0; char* lA1 = (char*)As + f1;
  char* lB0 = (char*)Bs + f0; char* lB1 = (char*)Bs + f1;
  const int fr = lane & 15, kb = (lane >> 4) * 16;
  const char* aptr[4]; const char* bptr[4];
#pragma unroll
  for (int i = 0; i < 4; ++i) {
    aptr[i] = (const char*)As + (wr * 64 + i * 16 + fr) * 64 + kb;
    bptr[i] = (const char*)Bs + (wc * 64 + i * 16 + fr) * 64 + kb;
  }
  f32x4 acc[4][4] = {};
  for (int kk = 0; kk < Kin; kk += 32) {
    const size_t ko = (size_t)kk * 2;
    gld_lds16(gA0 + ko, lA0); gld_lds16(gA1 + ko, lA1);
    gld_lds16(gB0 + ko, lB0); gld_lds16(gB1 + ko, lB1);
    __syncthreads();
    bf16x8 a[4], b[4];
#pragma unroll
    for (int i = 0; i < 4; ++i) a[i] = *(const bf16x8*)aptr[i];
#pragma unroll
    for (int i = 0; i < 4; ++i) b[i] = *(const bf16x8*)bptr[i];
#pragma unroll
    for (int mi = 0; mi < 4; ++mi)
#pragma unroll
      for (int ni = 0; ni < 4; ++ni)
        acc[mi][ni] = __builtin_amdgcn_mfma_f32_16x16x32_bf16(a[mi], b[ni], acc[mi][ni], 0, 0, 0);
    __syncthreads();
  }
  const int cm = (lane >> 4) * 4, cn = lane & 15;
  float bv[4];
#pragma unroll
  for (int ni = 0; ni < 4; ++ni) bv[ni] = bias[bcol + wc * 64 + ni * 16 + cn];
#pragma unroll
  for (int mi = 0; mi < 4; ++mi) {
    const long row0 = brow + wr * 64 + mi * 16 + cm;
#pragma unroll
    for (int ni = 0; ni < 4; ++ni) {
      const long col = bcol + wc * 64 + ni * 16 + cn;
#pragma unroll
      for (int j = 0; j < 4; ++j)
        C[(row0 + j) * (long)Nout + col] = acc[mi][ni][j] + bv[ni];
    }
  }
}

// ---- naive fallback --------------------------------------------------------
__global__ void fallback_kernel(const float* __restrict__ x, const float* __restrict__ values,
                                const int* __restrict__ widx, const float* __restrict__ bias,
                                float* __restrict__ out, const int* __restrict__ flag,
                                int NT, int IF, int OF) {
  const int o = blockIdx.x * blockDim.x + threadIdx.x;
  const int t = blockIdx.y;
  if (o >= OF || t >= NT) return;
  const bool is32 = (*flag != 0);
  const float* xr = x + (size_t)t * IF;
  float sum = 0.f;
  if (is32) {
    const int* w = widx + (size_t)o * IF;
    for (int k = 0; k < IF; ++k) sum += xr[k] * values[w[k]];
  } else {
    const long long* w = (const long long*)widx + (size_t)o * IF;
    for (int k = 0; k < IF; ++k) sum += xr[k] * values[(int)w[k]];
  }
  out[(size_t)t * OF + o] = sum + bias[o];
}

extern "C" void kernel_launch(void* const* d_in, const int* in_sizes, int n_in,
                              void* d_out, int out_size, void* d_ws, size_t ws_size,
                              hipStream_t stream) {
  const float* x      = (const float*)d_in[0];
  const float* values = (const float*)d_in[1];
  const int*   widx   = (const int*)d_in[2];
  const float* bias   = (const float*)d_in[3];
  float* out = (float*)d_out;

  const long xsz = in_sizes[0];
  const int  OF  = in_sizes[3];
  const long wsz = in_sizes[2];
  const int  IF  = (int)(wsz / OF);
  const int  NTOK = (int)(xsz / IF);

  u16* xb = (u16*)d_ws;
  u16* wb = xb + (size_t)NTOK * IF;
  int* flag = (int*)(wb + (size_t)OF * IF);
  const size_t need = ((size_t)NTOK * IF + (size_t)OF * IF) * sizeof(u16) + 64;

  const bool pre_ok = (ws_size >= need) && ((xsz % 8) == 0) && ((wsz % 4) == 0);
  const bool f256 = pre_ok && (IF % 128 == 0) && (IF >= 256) &&
                    (NTOK % 256 == 0) && (OF % 256 == 0);
  const bool f128 = pre_ok && (IF % 32 == 0) && (NTOK % 128 == 0) && (OF % 128 == 0);

  if (f256 || f128) {
    hipLaunchKernelGGL(detect_idx_width, dim3(1), dim3(64), 0, stream,
                       (const unsigned*)widx, flag);
    hipLaunchKernelGGL(cvt_x_kernel, dim3(2048), dim3(256), 0, stream,
                       (const float4*)x, xb, xsz / 8);
    hipLaunchKernelGGL(dequant_w_kernel, dim3(2048), dim3(256), 0, stream,
                       (const int4*)widx, values, wb, (const int*)flag, wsz / 4);
    if (f256) {
      const int grid = (NTOK / 256) * (OF / 256);
      hipLaunchKernelGGL(gemm256_kernel, dim3(grid), dim3(512), 0, stream,
                         xb, wb, bias, out, OF, IF);
    } else {
      const int grid = (NTOK / 128) * (OF / 128);
      hipLaunchKernelGGL(gemm128_kernel, dim3(grid), dim3(256), 0, stream,
                         xb, wb, bias, out, OF, IF);
    }
  } else {
    int* flag2 = (int*)d_ws;
    hipLaunchKernelGGL(detect_idx_width, dim3(1), dim3(64), 0, stream,
                       (const unsigned*)widx, flag2);
    hipLaunchKernelGGL(fallback_kernel, dim3((OF + 255) / 256, NTOK), dim3(256), 0, stream,
                       x, values, widx, bias, out, (const int*)flag2, NTOK, IF, OF);
  }
}